// Round 3
// baseline (843.206 us; speedup 1.0000x reference)
//
#include <hip/hip_runtime.h>

typedef unsigned short u16;
typedef _Float16 f16;
typedef __attribute__((ext_vector_type(8))) f16 f16x8;
typedef __attribute__((ext_vector_type(4))) float fx4;
typedef __attribute__((ext_vector_type(8))) u16 u16x8;
typedef __attribute__((ext_vector_type(4))) u16 u16x4;

#define SZE 8388608u  // 16384*512 elements per [B*L, D] matrix

__device__ __forceinline__ u16 f2h_bits(float x) {
  union { f16 h; u16 u; } v; v.h = (f16)x; return v.u;
}

// async global->LDS, 16B per lane; dest is wave-uniform base + lane*16.
__device__ __forceinline__ void gl2lds16(const void* g, void* l) {
  __builtin_amdgcn_global_load_lds(
      (const __attribute__((address_space(1))) unsigned int*)g,
      (__attribute__((address_space(3))) unsigned int*)l, 16, 0, 0);
}

// ---------------- kernel 1: fp32 -> fp16 convert of both inputs ------------
__global__ __launch_bounds__(256) void convert_x(const float* __restrict__ x0,
                                                 const float* __restrict__ x1,
                                                 u16* __restrict__ xh) {
  size_t i = ((size_t)blockIdx.x * 256 + threadIdx.x) * 8;
  const float* src = (i < SZE) ? (x0 + i) : (x1 + (i - SZE));
  float4 a = *(const float4*)(src);
  float4 b = *(const float4*)(src + 4);
  u16x8 o;
  o[0] = f2h_bits(a.x); o[1] = f2h_bits(a.y);
  o[2] = f2h_bits(a.z); o[3] = f2h_bits(a.w);
  o[4] = f2h_bits(b.x); o[5] = f2h_bits(b.y);
  o[6] = f2h_bits(b.z); o[7] = f2h_bits(b.w);
  *(u16x8*)(xh + i) = o;
}

// ---------------- kernel 2: W [K][N] fp32 -> Wt [N][K] fp16 ----------------
__global__ __launch_bounds__(256) void wtrans(
    const float* __restrict__ w0, const float* __restrict__ w1,
    const float* __restrict__ w2, const float* __restrict__ w3,
    const float* __restrict__ w4, const float* __restrict__ w5,
    u16* __restrict__ wt) {
  __shared__ float tile[32][33];
  const int z = blockIdx.z;
  const float* W = z == 0 ? w0 : z == 1 ? w1 : z == 2 ? w2
                 : z == 3 ? w3 : z == 4 ? w4 : w5;
  u16* WT = wt + (size_t)z * 262144u;
  const int k0 = blockIdx.x * 32, n0 = blockIdx.y * 32;
  const int tx = threadIdx.x, ty = threadIdx.y;  // 32 x 8
  for (int j = 0; j < 32; j += 8)
    tile[ty + j][tx] = W[(size_t)(k0 + ty + j) * 512 + n0 + tx];
  __syncthreads();
  for (int j = 0; j < 32; j += 8)
    WT[(size_t)(n0 + ty + j) * 512 + k0 + tx] = f2h_bits(tile[tx][ty + j]);
}

// ---------------- kernel 3: six projections, C = X*W + b -------------------
__global__ __launch_bounds__(256, 2) void proj_gemm(
    const u16* __restrict__ xh, const u16* __restrict__ wt,
    u16* __restrict__ qkv,
    const float* __restrict__ b0, const float* __restrict__ b1,
    const float* __restrict__ b2, const float* __restrict__ b3,
    const float* __restrict__ b4, const float* __restrict__ b5) {
  const int proj = blockIdx.z;
  const u16* X = xh + (proj < 3 ? 0u : SZE);
  const u16* W = wt + (size_t)proj * 262144u;
  u16* out = qkv + (size_t)proj * SZE;
  const float* bias = proj == 0 ? b0 : proj == 1 ? b1 : proj == 2 ? b2
                    : proj == 3 ? b3 : proj == 4 ? b4 : b5;
  const int m0 = blockIdx.x * 128, n0 = blockIdx.y * 128;
  const int t = threadIdx.x, lane = t & 63, w = t >> 6;
  const int wr = w >> 1, wc = w & 1, ml = lane & 15, q = lane >> 4;
  __shared__ u16 sA[4096], sB[4096];
  fx4 acc[4][4] = {};
  for (int k0 = 0; k0 < 512; k0 += 32) {
    for (int r = 0; r < 2; ++r) {
      int c = r * 256 + t;
      int cq = c >> 7, cm = c & 127;
      gl2lds16(X + (size_t)(m0 + cm) * 512 + (k0 + cq * 8), sA + c * 8);
      gl2lds16(W + (size_t)(n0 + cm) * 512 + (k0 + cq * 8), sB + c * 8);
    }
    __syncthreads();
    f16x8 af[4], bf[4];
    for (int i = 0; i < 4; ++i) {
      af[i] = *(const f16x8*)(sA + (q * 128 + wr * 64 + i * 16 + ml) * 8);
      bf[i] = *(const f16x8*)(sB + (q * 128 + wc * 64 + i * 16 + ml) * 8);
    }
    for (int i = 0; i < 4; ++i)
      for (int j = 0; j < 4; ++j)
        acc[i][j] = __builtin_amdgcn_mfma_f32_16x16x32_f16(af[i], bf[j],
                                                           acc[i][j], 0, 0, 0);
    __syncthreads();
  }
  const bool vtrans = (proj % 3) == 2;
  for (int j = 0; j < 4; ++j) {
    const int n = n0 + wc * 64 + j * 16 + ml;
    const float bv = bias[n];
    for (int i = 0; i < 4; ++i) {
      const int mb = m0 + wr * 64 + i * 16 + q * 4;
      if (!vtrans) {
        for (int r = 0; r < 4; ++r)
          out[(size_t)(mb + r) * 512 + n] = f2h_bits(acc[i][j][r] + bv);
      } else {
        const int bb = mb >> 11, l = mb & 2047;
        u16x4 pk;
        for (int r = 0; r < 4; ++r) pk[r] = f2h_bits(acc[i][j][r] + bv);
        *(u16x4*)(out + ((size_t)bb * 512 + n) * 2048 + l) = pk;
      }
    }
  }
}

// ---------------- kernel 4: flash cross-attention v3 -----------------------
// 4 waves = 64 queries/block, 512 blocks (2 blocks/CU). Wave w owns rows
// w*16..w*16+15 for QK^T + online softmax (state in regs). PV is d-sliced:
// wave w computes acc for ALL 64 rows x d-slice [w*128, w*128+128), with V
// fragments loaded global->VGPR (zero redundancy, no LDS, no barrier dep).
// P and alpha cross shared double-buffered LDS; K double-buffered via
// global_load_lds staged one iter ahead -> barrier drain covered by compute.
// ONE barrier per iteration.
__global__ __launch_bounds__(256, 2) void attn_kernel(const u16* __restrict__ qkv,
                                                      float* __restrict__ out) {
  const int t = threadIdx.x, lane = t & 63, w = t >> 6;  // w in 0..3
  const int ml = lane & 15, q = lane >> 4;
  // XCD swizzle: xcd = n&7 owns (b,tt) groups {2*xcd, 2*xcd+1}
  const int n = blockIdx.x;
  const int xcd = n & 7, slot = n >> 3;
  const int g = xcd * 2 + (slot >> 5);
  const int qt = slot & 31;
  const int b = g >> 1, tt = g & 1;

  const u16* Q  = qkv + (tt ? (size_t)3 * SZE : (size_t)0);
  const u16* K  = qkv + (tt ? (size_t)1 * SZE : (size_t)4 * SZE);
  const u16* Vt = qkv + (tt ? (size_t)5 * SZE : (size_t)2 * SZE);
  float* O = out + (tt ? (size_t)SZE : (size_t)0) +
             ((size_t)b * 2048 + qt * 64) * 512;
  const u16* Qb = Q + ((size_t)b * 2048 + qt * 64) * 512;
  const u16* Kb = K + (size_t)b * 2048 * 512;
  const u16* Vb = Vt + (size_t)b * 512 * 2048;  // [D][L]

  __shared__ u16 sK[2][16384];   // 2 x 32KB, chunk p = dchunk*32 + key
  __shared__ u16 sP[2][2560];    // 2 x 64 rows x stride 40 (16B-aligned rows)
  __shared__ float aS[2][64];
  __shared__ float lS[64];

  // Q A-frags for this wave's 16 rows (64 VGPR, resident all 64 iters)
  f16x8 qf[16];
  {
    const u16* qrow = Qb + (size_t)(w * 16 + ml) * 512 + q * 8;
#pragma unroll
    for (int ks = 0; ks < 16; ++ks) qf[ks] = *(const f16x8*)(qrow + ks * 32);
  }
  const u16* vbase = Vb + (size_t)(w * 128 + ml) * 2048 + q * 8;

  fx4 acc[4][8] = {};  // [row-tile mt][d-subtile nj]: rows mt*16+q*4+r,
                       // col w*128 + nj*16 + ml
  fx4 mrun = {-3.0e38f, -3.0e38f, -3.0e38f, -3.0e38f};
  fx4 lrun = {0.f, 0.f, 0.f, 0.f};

  // prestage K tile 0
#pragma unroll
  for (int r = 0; r < 8; ++r) {
    int p = r * 256 + t;
    gl2lds16(Kb + (size_t)(p & 31) * 512 + (p >> 5) * 8, sK[0] + p * 8);
  }
  __syncthreads();

#pragma unroll 2
  for (int it = 0; it < 64; ++it) {
    const int c = it & 1;
    const int k0 = it * 32;
    // ---- stage K[it+1] into the other buffer (drained at this iter's
    //      barrier, i.e. with the whole QK^T+softmax phase as cover) ----
    if (it < 63) {
      const u16* Kn = Kb + (size_t)(k0 + 32) * 512;
#pragma unroll
      for (int r = 0; r < 8; ++r) {
        int p = r * 256 + t;
        gl2lds16(Kn + (size_t)(p & 31) * 512 + (p >> 5) * 8, sK[c ^ 1] + p * 8);
      }
    }
    // ---- V d-slice fragments, first half (global->VGPR, covered by QK^T) --
    f16x8 vfa[4];
#pragma unroll
    for (int nj = 0; nj < 4; ++nj)
      vfa[nj] = *(const f16x8*)(vbase + (size_t)(nj * 16) * 2048 + k0);
    // ---- QK^T: this wave's 16 rows x 32 keys ----
    fx4 s0 = {0.f, 0.f, 0.f, 0.f}, s1 = {0.f, 0.f, 0.f, 0.f};
#pragma unroll
    for (int ks = 0; ks < 16; ++ks) {
      f16x8 kf0 = *(const f16x8*)(sK[c] + ((ks * 4 + q) * 32 + ml) * 8);
      f16x8 kf1 = *(const f16x8*)(sK[c] + ((ks * 4 + q) * 32 + 16 + ml) * 8);
      s0 = __builtin_amdgcn_mfma_f32_16x16x32_f16(qf[ks], kf0, s0, 0, 0, 0);
      s1 = __builtin_amdgcn_mfma_f32_16x16x32_f16(qf[ks], kf1, s1, 0, 0, 0);
    }
    // ---- online softmax for owned rows (state in registers) ----
    fx4 mx, alpha, p0, p1, sm;
#pragma unroll
    for (int r = 0; r < 4; ++r) mx[r] = fmaxf(s0[r], s1[r]);
#pragma unroll
    for (int d = 1; d < 16; d <<= 1) {
      mx[0] = fmaxf(mx[0], __shfl_xor(mx[0], d));
      mx[1] = fmaxf(mx[1], __shfl_xor(mx[1], d));
      mx[2] = fmaxf(mx[2], __shfl_xor(mx[2], d));
      mx[3] = fmaxf(mx[3], __shfl_xor(mx[3], d));
    }
#pragma unroll
    for (int r = 0; r < 4; ++r) {
      float mn = fmaxf(mrun[r], mx[r]);
      alpha[r] = __expf(mrun[r] - mn);
      mrun[r] = mn;
      p0[r] = __expf(s0[r] - mn);
      p1[r] = __expf(s1[r] - mn);
      sm[r] = p0[r] + p1[r];
    }
#pragma unroll
    for (int d = 1; d < 16; d <<= 1) {
      sm[0] += __shfl_xor(sm[0], d);
      sm[1] += __shfl_xor(sm[1], d);
      sm[2] += __shfl_xor(sm[2], d);
      sm[3] += __shfl_xor(sm[3], d);
    }
#pragma unroll
    for (int r = 0; r < 4; ++r) lrun[r] = alpha[r] * lrun[r] + sm[r];
    // ---- publish P (A-layout rows, stride 40) and alpha ----
    {
      u16* wp = sP[c] + (w * 16 + q * 4) * 40;
#pragma unroll
      for (int r = 0; r < 4; ++r) {
        wp[r * 40 + ml] = f2h_bits(p0[r]);
        wp[r * 40 + 16 + ml] = f2h_bits(p1[r]);
      }
      if (ml == 0) {
#pragma unroll
        for (int r = 0; r < 4; ++r) aS[c][w * 16 + q * 4 + r] = alpha[r];
      }
    }
    __syncthreads();
    // ---- V second half (cover = rescale + first 16 PV MFMAs) ----
    f16x8 vfb[4];
#pragma unroll
    for (int nj = 0; nj < 4; ++nj)
      vfb[nj] = *(const f16x8*)(vbase + (size_t)(64 + nj * 16) * 2048 + k0);
    // ---- rescale acc by alpha (all 64 rows; skip when all alpha==1) ----
    f16x8 pf[4];
#pragma unroll
    for (int mt = 0; mt < 4; ++mt) {
      pf[mt] = *(const f16x8*)(sP[c] + (mt * 16 + ml) * 40 + q * 8);
      fx4 av = *(const fx4*)&aS[c][mt * 16 + q * 4];
      if (__any(av[0] != 1.f || av[1] != 1.f || av[2] != 1.f || av[3] != 1.f)) {
#pragma unroll
        for (int nj = 0; nj < 8; ++nj) {
          acc[mt][nj][0] *= av[0]; acc[mt][nj][1] *= av[1];
          acc[mt][nj][2] *= av[2]; acc[mt][nj][3] *= av[3];
        }
      }
    }
    // ---- PV: acc[mt][nj] += P[mt] * V[nj-th 16-d slab] ----
#pragma unroll
    for (int mt = 0; mt < 4; ++mt)
#pragma unroll
      for (int nj = 0; nj < 4; ++nj)
        acc[mt][nj] = __builtin_amdgcn_mfma_f32_16x16x32_f16(pf[mt], vfa[nj],
                                                             acc[mt][nj], 0, 0, 0);
#pragma unroll
    for (int mt = 0; mt < 4; ++mt)
#pragma unroll
      for (int nj = 0; nj < 4; ++nj)
        acc[mt][nj + 4] = __builtin_amdgcn_mfma_f32_16x16x32_f16(pf[mt], vfb[nj],
                                                                 acc[mt][nj + 4], 0, 0, 0);
  }
  // ---- share l, normalize, store ----
  if (ml == 0) {
#pragma unroll
    for (int r = 0; r < 4; ++r) lS[w * 16 + q * 4 + r] = lrun[r];
  }
  __syncthreads();
#pragma unroll
  for (int mt = 0; mt < 4; ++mt) {
    fx4 lv = *(const fx4*)&lS[mt * 16 + q * 4];
    fx4 li;
#pragma unroll
    for (int r = 0; r < 4; ++r) li[r] = 1.0f / lv[r];
    float* Ob = O + (size_t)(mt * 16 + q * 4) * 512 + w * 128 + ml;
#pragma unroll
    for (int nj = 0; nj < 8; ++nj) {
#pragma unroll
      for (int r = 0; r < 4; ++r)
        Ob[(size_t)r * 512 + nj * 16] = acc[mt][nj][r] * li[r];
    }
  }
}

extern "C" void kernel_launch(void* const* d_in, const int* in_sizes, int n_in,
                              void* d_out, int out_size, void* d_ws, size_t ws_size,
                              hipStream_t stream) {
  // ws layout (u16 elems): [xh: 2*SZE][wt: 6*512*512][qkv: 6*SZE]
  //   qkv order: 0=Qr 1=Kr 2=Vr^T 3=Qh 4=Kh 5=Vh^T
  u16* ws = (u16*)d_ws;
  u16* xh = ws;
  u16* wt = ws + 16777216u;            // 2*SZE
  u16* qkv = ws + 18350080u;           // 2*SZE + 6*262144

  convert_x<<<8192, 256, 0, stream>>>((const float*)d_in[0],
                                      (const float*)d_in[1], xh);
  wtrans<<<dim3(16, 16, 6), dim3(32, 8), 0, stream>>>(
      (const float*)d_in[2], (const float*)d_in[4], (const float*)d_in[6],
      (const float*)d_in[8], (const float*)d_in[10], (const float*)d_in[12], wt);
  proj_gemm<<<dim3(128, 4, 6), 256, 0, stream>>>(
      xh, wt, qkv,
      (const float*)d_in[3], (const float*)d_in[5], (const float*)d_in[7],
      (const float*)d_in[9], (const float*)d_in[11], (const float*)d_in[13]);
  attn_kernel<<<512, 256, 0, stream>>>(qkv, (float*)d_out);
}

// Round 4
// 689.372 us; speedup vs baseline: 1.2232x; 1.2232x over previous
//
#include <hip/hip_runtime.h>

typedef unsigned short u16;
typedef _Float16 f16;
typedef __attribute__((ext_vector_type(8))) f16 f16x8;
typedef __attribute__((ext_vector_type(4))) float fx4;
typedef __attribute__((ext_vector_type(8))) u16 u16x8;
typedef __attribute__((ext_vector_type(4))) u16 u16x4;

#define SZE 8388608u  // 16384*512 elements per [B*L, D] matrix

__device__ __forceinline__ u16 f2h_bits(float x) {
  union { f16 h; u16 u; } v; v.h = (f16)x; return v.u;
}

// async global->LDS, 16B per lane; dest is wave-uniform base + lane*16.
__device__ __forceinline__ void gl2lds16(const void* g, void* l) {
  __builtin_amdgcn_global_load_lds(
      (const __attribute__((address_space(1))) unsigned int*)g,
      (__attribute__((address_space(3))) unsigned int*)l, 16, 0, 0);
}

// ---------------- kernel 1: fp32 -> fp16 convert of both inputs ------------
__global__ __launch_bounds__(256) void convert_x(const float* __restrict__ x0,
                                                 const float* __restrict__ x1,
                                                 u16* __restrict__ xh) {
  size_t i = ((size_t)blockIdx.x * 256 + threadIdx.x) * 8;
  const float* src = (i < SZE) ? (x0 + i) : (x1 + (i - SZE));
  float4 a = *(const float4*)(src);
  float4 b = *(const float4*)(src + 4);
  u16x8 o;
  o[0] = f2h_bits(a.x); o[1] = f2h_bits(a.y);
  o[2] = f2h_bits(a.z); o[3] = f2h_bits(a.w);
  o[4] = f2h_bits(b.x); o[5] = f2h_bits(b.y);
  o[6] = f2h_bits(b.z); o[7] = f2h_bits(b.w);
  *(u16x8*)(xh + i) = o;
}

// ---------------- kernel 2: W [K][N] fp32 -> Wt [N][K] fp16 ----------------
__global__ __launch_bounds__(256) void wtrans(
    const float* __restrict__ w0, const float* __restrict__ w1,
    const float* __restrict__ w2, const float* __restrict__ w3,
    const float* __restrict__ w4, const float* __restrict__ w5,
    u16* __restrict__ wt) {
  __shared__ float tile[32][33];
  const int z = blockIdx.z;
  const float* W = z == 0 ? w0 : z == 1 ? w1 : z == 2 ? w2
                 : z == 3 ? w3 : z == 4 ? w4 : w5;
  u16* WT = wt + (size_t)z * 262144u;
  const int k0 = blockIdx.x * 32, n0 = blockIdx.y * 32;
  const int tx = threadIdx.x, ty = threadIdx.y;  // 32 x 8
  for (int j = 0; j < 32; j += 8)
    tile[ty + j][tx] = W[(size_t)(k0 + ty + j) * 512 + n0 + tx];
  __syncthreads();
  for (int j = 0; j < 32; j += 8)
    WT[(size_t)(n0 + ty + j) * 512 + k0 + tx] = f2h_bits(tile[tx][ty + j]);
}

// ---------------- kernel 3: six projections, C = X*W + b -------------------
__global__ __launch_bounds__(256, 2) void proj_gemm(
    const u16* __restrict__ xh, const u16* __restrict__ wt,
    u16* __restrict__ qkv,
    const float* __restrict__ b0, const float* __restrict__ b1,
    const float* __restrict__ b2, const float* __restrict__ b3,
    const float* __restrict__ b4, const float* __restrict__ b5) {
  const int proj = blockIdx.z;
  const u16* X = xh + (proj < 3 ? 0u : SZE);
  const u16* W = wt + (size_t)proj * 262144u;
  u16* out = qkv + (size_t)proj * SZE;
  const float* bias = proj == 0 ? b0 : proj == 1 ? b1 : proj == 2 ? b2
                    : proj == 3 ? b3 : proj == 4 ? b4 : b5;
  const int m0 = blockIdx.x * 128, n0 = blockIdx.y * 128;
  const int t = threadIdx.x, lane = t & 63, w = t >> 6;
  const int wr = w >> 1, wc = w & 1, ml = lane & 15, q = lane >> 4;
  __shared__ u16 sA[4096], sB[4096];
  fx4 acc[4][4] = {};
  for (int k0 = 0; k0 < 512; k0 += 32) {
    for (int r = 0; r < 2; ++r) {
      int c = r * 256 + t;
      int cq = c >> 7, cm = c & 127;
      gl2lds16(X + (size_t)(m0 + cm) * 512 + (k0 + cq * 8), sA + c * 8);
      gl2lds16(W + (size_t)(n0 + cm) * 512 + (k0 + cq * 8), sB + c * 8);
    }
    __syncthreads();
    f16x8 af[4], bf[4];
    for (int i = 0; i < 4; ++i) {
      af[i] = *(const f16x8*)(sA + (q * 128 + wr * 64 + i * 16 + ml) * 8);
      bf[i] = *(const f16x8*)(sB + (q * 128 + wc * 64 + i * 16 + ml) * 8);
    }
    for (int i = 0; i < 4; ++i)
      for (int j = 0; j < 4; ++j)
        acc[i][j] = __builtin_amdgcn_mfma_f32_16x16x32_f16(af[i], bf[j],
                                                           acc[i][j], 0, 0, 0);
    __syncthreads();
  }
  const bool vtrans = (proj % 3) == 2;
  for (int j = 0; j < 4; ++j) {
    const int n = n0 + wc * 64 + j * 16 + ml;
    const float bv = bias[n];
    for (int i = 0; i < 4; ++i) {
      const int mb = m0 + wr * 64 + i * 16 + q * 4;
      if (!vtrans) {
        for (int r = 0; r < 4; ++r)
          out[(size_t)(mb + r) * 512 + n] = f2h_bits(acc[i][j][r] + bv);
      } else {
        const int bb = mb >> 11, l = mb & 2047;
        u16x4 pk;
        for (int r = 0; r < 4; ++r) pk[r] = f2h_bits(acc[i][j][r] + bv);
        *(u16x4*)(out + ((size_t)bb * 512 + n) * 2048 + l) = pk;
      }
    }
  }
}

// ---------------- kernel 4: flash cross-attention v4 -----------------------
// Lockstep LDS design (R2) + pipelined staging + d-sliced V/P (low LDS vol).
// 8 waves = 128 queries/block, 256 blocks = 1 block/CU. Wave w owns rows
// [16w,16w+16) for QK^T + online softmax (state in regs). PV is d-sliced:
// wave w computes acc for ALL 128 rows x d-cols [64w, 64w+64) -> V LDS reads
// are exact (no redundancy). K double-buffered: K[it+1] staged at iter top,
// drained at MID barrier (cover = whole QK^T+softmax). V[it]/P single-buffered
// with the same cover. All blocks of a (b,tt) group run the same K/V tiles in
// lockstep on one XCD -> L2-resident stream (the property R3 broke).
__global__ __launch_bounds__(512, 2) void attn_kernel(const u16* __restrict__ qkv,
                                                      float* __restrict__ out) {
  const int t = threadIdx.x, lane = t & 63, w = t >> 6;  // w in 0..7
  const int ml = lane & 15, q = lane >> 4;
  // XCD swizzle: xcd = n&7 owns (b,tt) groups {2*xcd, 2*xcd+1}
  const int n = blockIdx.x;
  const int xcd = n & 7, slot = n >> 3;
  const int g = xcd * 2 + (slot >> 4);
  const int qt = slot & 15;
  const int b = g >> 1, tt = g & 1;

  const u16* Q  = qkv + (tt ? (size_t)3 * SZE : (size_t)0);
  const u16* K  = qkv + (tt ? (size_t)1 * SZE : (size_t)4 * SZE);
  const u16* Vt = qkv + (tt ? (size_t)5 * SZE : (size_t)2 * SZE);
  float* O = out + (tt ? (size_t)SZE : (size_t)0) +
             ((size_t)b * 2048 + qt * 128) * 512;
  const u16* Qb = Q + ((size_t)b * 2048 + qt * 128) * 512;
  const u16* Kb = K + (size_t)b * 2048 * 512;
  const u16* Vb = Vt + (size_t)b * 512 * 2048;  // [D][L]

  __shared__ u16 sK[2][16384];   // 2 x 32KB, chunk p = dchunk*32 + key
  __shared__ u16 sV[16384];      // 32KB, chunk p = kc*512 + d (kc = key/8)
  __shared__ u16 sP[5120];       // 128 rows x stride 40 halves
  __shared__ float aS[128], lS[128];

  // Q A-frags for this wave's 16 rows (64 VGPR, resident all 64 iters)
  f16x8 qf[16];
  {
    const u16* qrow = Qb + (size_t)(w * 16 + ml) * 512 + q * 8;
#pragma unroll
    for (int ks = 0; ks < 16; ++ks) qf[ks] = *(const f16x8*)(qrow + ks * 32);
  }

  fx4 acc[8][4] = {};  // [row-tile mt][nj]: rows mt*16+q*4+r,
                       // col w*64 + nj*16 + ml   (128 VGPR)
  fx4 mrun = {-3.0e38f, -3.0e38f, -3.0e38f, -3.0e38f};
  fx4 lrun = {0.f, 0.f, 0.f, 0.f};

  // prestage K tile 0 (drained by the pre-loop barrier)
#pragma unroll
  for (int r = 0; r < 4; ++r) {
    int p = r * 512 + t;
    gl2lds16(Kb + (size_t)(p & 31) * 512 + (p >> 5) * 8, sK[0] + p * 8);
  }
  __syncthreads();

#pragma unroll 2
  for (int it = 0; it < 64; ++it) {
    const int c = it & 1;
    const int k0 = it * 32;
    const u16* sKc = sK[c];
    // ---- stage V[it] (consumed after mid barrier of THIS iter) ----
#pragma unroll
    for (int r = 0; r < 4; ++r) {
      int p = r * 512 + t;
      gl2lds16(Vb + (size_t)(p & 511) * 2048 + k0 + (p >> 9) * 8, sV + p * 8);
    }
    // ---- stage K[it+1] into other buffer (drained at mid barrier; read
    //      next iteration — cover = QK^T + softmax) ----
    if (it < 63) {
      const u16* Kn = Kb + (size_t)(k0 + 32) * 512;
#pragma unroll
      for (int r = 0; r < 4; ++r) {
        int p = r * 512 + t;
        gl2lds16(Kn + (size_t)(p & 31) * 512 + (p >> 5) * 8, sK[c ^ 1] + p * 8);
      }
    }
    // ---- QK^T: this wave's 16 rows x 32 keys ----
    fx4 s0 = {0.f, 0.f, 0.f, 0.f}, s1 = {0.f, 0.f, 0.f, 0.f};
#pragma unroll
    for (int ks = 0; ks < 16; ++ks) {
      f16x8 kf0 = *(const f16x8*)(sKc + ((ks * 4 + q) * 32 + ml) * 8);
      f16x8 kf1 = *(const f16x8*)(sKc + ((ks * 4 + q) * 32 + 16 + ml) * 8);
      s0 = __builtin_amdgcn_mfma_f32_16x16x32_f16(qf[ks], kf0, s0, 0, 0, 0);
      s1 = __builtin_amdgcn_mfma_f32_16x16x32_f16(qf[ks], kf1, s1, 0, 0, 0);
    }
    // ---- online softmax for owned rows (state in registers) ----
    fx4 mx, alpha, p0, p1, sm;
#pragma unroll
    for (int r = 0; r < 4; ++r) mx[r] = fmaxf(s0[r], s1[r]);
#pragma unroll
    for (int d = 1; d < 16; d <<= 1) {
      mx[0] = fmaxf(mx[0], __shfl_xor(mx[0], d));
      mx[1] = fmaxf(mx[1], __shfl_xor(mx[1], d));
      mx[2] = fmaxf(mx[2], __shfl_xor(mx[2], d));
      mx[3] = fmaxf(mx[3], __shfl_xor(mx[3], d));
    }
#pragma unroll
    for (int r = 0; r < 4; ++r) {
      float mn = fmaxf(mrun[r], mx[r]);
      alpha[r] = __expf(mrun[r] - mn);
      mrun[r] = mn;
      p0[r] = __expf(s0[r] - mn);
      p1[r] = __expf(s1[r] - mn);
      sm[r] = p0[r] + p1[r];
    }
#pragma unroll
    for (int d = 1; d < 16; d <<= 1) {
      sm[0] += __shfl_xor(sm[0], d);
      sm[1] += __shfl_xor(sm[1], d);
      sm[2] += __shfl_xor(sm[2], d);
      sm[3] += __shfl_xor(sm[3], d);
    }
#pragma unroll
    for (int r = 0; r < 4; ++r) lrun[r] = alpha[r] * lrun[r] + sm[r];
    // ---- publish P (A-layout rows, stride 40) and alpha ----
    {
      u16* wp = sP + (w * 16 + q * 4) * 40;
#pragma unroll
      for (int r = 0; r < 4; ++r) {
        wp[r * 40 + ml] = f2h_bits(p0[r]);
        wp[r * 40 + 16 + ml] = f2h_bits(p1[r]);
      }
      if (ml == 0) {
#pragma unroll
        for (int r = 0; r < 4; ++r) aS[w * 16 + q * 4 + r] = alpha[r];
      }
    }
    __syncthreads();  // drains staging (V[it], K[it+1]) + publishes P/alpha
    // ---- V B-frags for this wave's 64-d slice (exact, no redundancy) ----
    f16x8 vf[4];
#pragma unroll
    for (int nj = 0; nj < 4; ++nj)
      vf[nj] = *(const f16x8*)(sV + (q * 512 + w * 64 + nj * 16 + ml) * 8);
    // ---- rescale + PV over all 8 row-tiles ----
#pragma unroll
    for (int mt = 0; mt < 8; ++mt) {
      fx4 av = *(const fx4*)&aS[mt * 16 + q * 4];
      if (__any(av[0] != 1.f || av[1] != 1.f || av[2] != 1.f || av[3] != 1.f)) {
#pragma unroll
        for (int nj = 0; nj < 4; ++nj) {
          acc[mt][nj][0] *= av[0]; acc[mt][nj][1] *= av[1];
          acc[mt][nj][2] *= av[2]; acc[mt][nj][3] *= av[3];
        }
      }
      f16x8 pf = *(const f16x8*)(sP + (mt * 16 + ml) * 40 + q * 8);
#pragma unroll
      for (int nj = 0; nj < 4; ++nj)
        acc[mt][nj] = __builtin_amdgcn_mfma_f32_16x16x32_f16(pf, vf[nj],
                                                             acc[mt][nj], 0, 0, 0);
    }
    __syncthreads();  // sP/sV/aS reads done before next-iter rewrite
  }
  // ---- share l, normalize, store ----
  if (ml == 0) {
#pragma unroll
    for (int r = 0; r < 4; ++r) lS[w * 16 + q * 4 + r] = lrun[r];
  }
  __syncthreads();
#pragma unroll
  for (int mt = 0; mt < 8; ++mt) {
    fx4 lv = *(const fx4*)&lS[mt * 16 + q * 4];
    fx4 li;
#pragma unroll
    for (int r = 0; r < 4; ++r) li[r] = 1.0f / lv[r];
    float* Ob = O + (size_t)(mt * 16 + q * 4) * 512 + w * 64 + ml;
#pragma unroll
    for (int nj = 0; nj < 4; ++nj) {
#pragma unroll
      for (int r = 0; r < 4; ++r)
        Ob[(size_t)r * 512 + nj * 16] = acc[mt][nj][r] * li[r];
    }
  }
}

extern "C" void kernel_launch(void* const* d_in, const int* in_sizes, int n_in,
                              void* d_out, int out_size, void* d_ws, size_t ws_size,
                              hipStream_t stream) {
  // ws layout (u16 elems): [xh: 2*SZE][wt: 6*512*512][qkv: 6*SZE]
  //   qkv order: 0=Qr 1=Kr 2=Vr^T 3=Qh 4=Kh 5=Vh^T
  u16* ws = (u16*)d_ws;
  u16* xh = ws;
  u16* wt = ws + 16777216u;            // 2*SZE
  u16* qkv = ws + 18350080u;           // 2*SZE + 6*262144

  convert_x<<<8192, 256, 0, stream>>>((const float*)d_in[0],
                                      (const float*)d_in[1], xh);
  wtrans<<<dim3(16, 16, 6), dim3(32, 8), 0, stream>>>(
      (const float*)d_in[2], (const float*)d_in[4], (const float*)d_in[6],
      (const float*)d_in[8], (const float*)d_in[10], (const float*)d_in[12], wt);
  proj_gemm<<<dim3(128, 4, 6), 256, 0, stream>>>(
      xh, wt, qkv,
      (const float*)d_in[3], (const float*)d_in[5], (const float*)d_in[7],
      (const float*)d_in[9], (const float*)d_in[11], (const float*)d_in[13]);
  attn_kernel<<<256, 512, 0, stream>>>(qkv, (float*)d_out);
}

// Round 5
// 552.145 us; speedup vs baseline: 1.5271x; 1.2485x over previous
//
#include <hip/hip_runtime.h>

typedef unsigned short u16;
typedef _Float16 f16;
typedef __attribute__((ext_vector_type(8))) f16 f16x8;
typedef __attribute__((ext_vector_type(4))) float fx4;
typedef __attribute__((ext_vector_type(8))) u16 u16x8;
typedef __attribute__((ext_vector_type(4))) u16 u16x4;

#define SZE 8388608u  // 16384*512 elements per [B*L, D] matrix

__device__ __forceinline__ u16 f2h_bits(float x) {
  union { f16 h; u16 u; } v; v.h = (f16)x; return v.u;
}

// async global->LDS, 16B per lane; dest is wave-uniform base + lane*16.
__device__ __forceinline__ void gl2lds16(const void* g, void* l) {
  __builtin_amdgcn_global_load_lds(
      (const __attribute__((address_space(1))) unsigned int*)g,
      (__attribute__((address_space(3))) unsigned int*)l, 16, 0, 0);
}

// ---------------- kernel 1: fp32 -> fp16 convert of both inputs ------------
__global__ __launch_bounds__(256) void convert_x(const float* __restrict__ x0,
                                                 const float* __restrict__ x1,
                                                 u16* __restrict__ xh) {
  size_t i = ((size_t)blockIdx.x * 256 + threadIdx.x) * 8;
  const float* src = (i < SZE) ? (x0 + i) : (x1 + (i - SZE));
  float4 a = *(const float4*)(src);
  float4 b = *(const float4*)(src + 4);
  u16x8 o;
  o[0] = f2h_bits(a.x); o[1] = f2h_bits(a.y);
  o[2] = f2h_bits(a.z); o[3] = f2h_bits(a.w);
  o[4] = f2h_bits(b.x); o[5] = f2h_bits(b.y);
  o[6] = f2h_bits(b.z); o[7] = f2h_bits(b.w);
  *(u16x8*)(xh + i) = o;
}

// ---------------- kernel 2: W [K][N] fp32 -> Wt [N][K] fp16 ----------------
__global__ __launch_bounds__(256) void wtrans(
    const float* __restrict__ w0, const float* __restrict__ w1,
    const float* __restrict__ w2, const float* __restrict__ w3,
    const float* __restrict__ w4, const float* __restrict__ w5,
    u16* __restrict__ wt) {
  __shared__ float tile[32][33];
  const int z = blockIdx.z;
  const float* W = z == 0 ? w0 : z == 1 ? w1 : z == 2 ? w2
                 : z == 3 ? w3 : z == 4 ? w4 : w5;
  u16* WT = wt + (size_t)z * 262144u;
  const int k0 = blockIdx.x * 32, n0 = blockIdx.y * 32;
  const int tx = threadIdx.x, ty = threadIdx.y;  // 32 x 8
  for (int j = 0; j < 32; j += 8)
    tile[ty + j][tx] = W[(size_t)(k0 + ty + j) * 512 + n0 + tx];
  __syncthreads();
  for (int j = 0; j < 32; j += 8)
    WT[(size_t)(n0 + ty + j) * 512 + k0 + tx] = f2h_bits(tile[tx][ty + j]);
}

// ---------------- kernel 3: six projections, C = X*W + b -------------------
__global__ __launch_bounds__(256, 2) void proj_gemm(
    const u16* __restrict__ xh, const u16* __restrict__ wt,
    u16* __restrict__ qkv,
    const float* __restrict__ b0, const float* __restrict__ b1,
    const float* __restrict__ b2, const float* __restrict__ b3,
    const float* __restrict__ b4, const float* __restrict__ b5) {
  const int proj = blockIdx.z;
  const u16* X = xh + (proj < 3 ? 0u : SZE);
  const u16* W = wt + (size_t)proj * 262144u;
  u16* out = qkv + (size_t)proj * SZE;
  const float* bias = proj == 0 ? b0 : proj == 1 ? b1 : proj == 2 ? b2
                    : proj == 3 ? b3 : proj == 4 ? b4 : b5;
  const int m0 = blockIdx.x * 128, n0 = blockIdx.y * 128;
  const int t = threadIdx.x, lane = t & 63, w = t >> 6;
  const int wr = w >> 1, wc = w & 1, ml = lane & 15, q = lane >> 4;
  __shared__ u16 sA[4096], sB[4096];
  fx4 acc[4][4] = {};
  for (int k0 = 0; k0 < 512; k0 += 32) {
    for (int r = 0; r < 2; ++r) {
      int c = r * 256 + t;
      int cq = c >> 7, cm = c & 127;
      gl2lds16(X + (size_t)(m0 + cm) * 512 + (k0 + cq * 8), sA + c * 8);
      gl2lds16(W + (size_t)(n0 + cm) * 512 + (k0 + cq * 8), sB + c * 8);
    }
    __syncthreads();
    f16x8 af[4], bf[4];
    for (int i = 0; i < 4; ++i) {
      af[i] = *(const f16x8*)(sA + (q * 128 + wr * 64 + i * 16 + ml) * 8);
      bf[i] = *(const f16x8*)(sB + (q * 128 + wc * 64 + i * 16 + ml) * 8);
    }
    for (int i = 0; i < 4; ++i)
      for (int j = 0; j < 4; ++j)
        acc[i][j] = __builtin_amdgcn_mfma_f32_16x16x32_f16(af[i], bf[j],
                                                           acc[i][j], 0, 0, 0);
    __syncthreads();
  }
  const bool vtrans = (proj % 3) == 2;
  for (int j = 0; j < 4; ++j) {
    const int n = n0 + wc * 64 + j * 16 + ml;
    const float bv = bias[n];
    for (int i = 0; i < 4; ++i) {
      const int mb = m0 + wr * 64 + i * 16 + q * 4;
      if (!vtrans) {
        for (int r = 0; r < 4; ++r)
          out[(size_t)(mb + r) * 512 + n] = f2h_bits(acc[i][j][r] + bv);
      } else {
        const int bb = mb >> 11, l = mb & 2047;
        u16x4 pk;
        for (int r = 0; r < 4; ++r) pk[r] = f2h_bits(acc[i][j][r] + bv);
        *(u16x4*)(out + ((size_t)bb * 512 + n) * 2048 + l) = pk;
      }
    }
  }
}

// ---------------- kernel 4: flash cross-attention v5 -----------------------
// Wave-autonomous (R2) + fully covered staging, ONE barrier/iter.
// 8 waves = 128 queries/block, 256 blocks = 1 block/CU. Wave w owns rows
// [16w,16w+16) END-TO-END: QK^T, softmax (regs), P (private LDS slab, no
// barrier), PV over all 512 d. K and V both double-buffered: tile it+1 staged
// at top of iter it, drained by the single end-of-iter barrier (cover = the
// whole iteration >> L2 latency). No mid barrier -> waves drift across the
// iteration and overlap MFMA/VALU/LDS pipes (the property R4's mid barrier
// destroyed). Lockstep tile sharing across the group's 16 blocks keeps the
// K/V stream L2-resident (the property R3 broke).
__global__ __launch_bounds__(512, 2) void attn_kernel(const u16* __restrict__ qkv,
                                                      float* __restrict__ out) {
  const int t = threadIdx.x, lane = t & 63, w = t >> 6;  // w in 0..7
  const int ml = lane & 15, q = lane >> 4;
  // XCD swizzle: xcd = n&7 owns (b,tt) groups {2*xcd, 2*xcd+1}
  const int n = blockIdx.x;
  const int xcd = n & 7, slot = n >> 3;
  const int g = xcd * 2 + (slot >> 4);
  const int qt = slot & 15;
  const int b = g >> 1, tt = g & 1;

  const u16* Q  = qkv + (tt ? (size_t)3 * SZE : (size_t)0);
  const u16* K  = qkv + (tt ? (size_t)1 * SZE : (size_t)4 * SZE);
  const u16* Vt = qkv + (tt ? (size_t)5 * SZE : (size_t)2 * SZE);
  float* O = out + (tt ? (size_t)SZE : (size_t)0) +
             ((size_t)b * 2048 + qt * 128) * 512;
  const u16* Qb = Q + ((size_t)b * 2048 + qt * 128) * 512;
  const u16* Kb = K + (size_t)b * 2048 * 512;
  const u16* Vb = Vt + (size_t)b * 512 * 2048;  // [D][L]

  __shared__ u16 sK[2][16384];   // 2 x 32KB, chunk p: [dchunk(64)][key(32)]
  __shared__ u16 sV[2][16384];   // 2 x 32KB, chunk p: [kc(4)][d(512)]
  __shared__ u16 sP[8 * 640];    // per-wave 16 rows x stride 40

  // Q A-frags for this wave's 16 rows (64 VGPR, resident all 64 iters)
  f16x8 qf[16];
  {
    const u16* qrow = Qb + (size_t)(w * 16 + ml) * 512 + q * 8;
#pragma unroll
    for (int ks = 0; ks < 16; ++ks) qf[ks] = *(const f16x8*)(qrow + ks * 32);
  }

  fx4 acc[32] = {};  // rows q*4+r (of wave's 16), col nj*16+ml  (128 VGPR)
  fx4 mrun = {-3.0e38f, -3.0e38f, -3.0e38f, -3.0e38f};
  fx4 lrun = {0.f, 0.f, 0.f, 0.f};
  u16* wp = sP + w * 640;

  // prestage K[0], V[0] into buffer 0
#pragma unroll
  for (int r = 0; r < 4; ++r) {
    int p = r * 512 + t;
    gl2lds16(Kb + (size_t)(p & 31) * 512 + (p >> 5) * 8, sK[0] + p * 8);
    gl2lds16(Vb + (size_t)(p & 511) * 2048 + (p >> 9) * 8, sV[0] + p * 8);
  }
  __syncthreads();

  for (int it = 0; it < 64; ++it) {
    const int c = it & 1;
    const int k0 = it * 32;
    const u16* sKc = sK[c];
    const u16* sVc = sV[c];
    // ---- stage K[it+1], V[it+1] into other buffer; drained at THIS iter's
    //      single end barrier (cover = entire iteration) ----
    if (it < 63) {
      const u16* Kn = Kb + (size_t)(k0 + 32) * 512;
      const u16* Vn = Vb + (size_t)(k0 + 32);
#pragma unroll
      for (int r = 0; r < 4; ++r) {
        int p = r * 512 + t;
        gl2lds16(Kn + (size_t)(p & 31) * 512 + (p >> 5) * 8, sK[c ^ 1] + p * 8);
        gl2lds16(Vn + (size_t)(p & 511) * 2048 + (p >> 9) * 8, sV[c ^ 1] + p * 8);
      }
    }
    // ---- QK^T: this wave's 16 rows x 32 keys ----
    fx4 s0 = {0.f, 0.f, 0.f, 0.f}, s1 = {0.f, 0.f, 0.f, 0.f};
#pragma unroll
    for (int ks = 0; ks < 16; ++ks) {
      f16x8 kf0 = *(const f16x8*)(sKc + ((ks * 4 + q) * 32 + ml) * 8);
      f16x8 kf1 = *(const f16x8*)(sKc + ((ks * 4 + q) * 32 + 16 + ml) * 8);
      s0 = __builtin_amdgcn_mfma_f32_16x16x32_f16(qf[ks], kf0, s0, 0, 0, 0);
      s1 = __builtin_amdgcn_mfma_f32_16x16x32_f16(qf[ks], kf1, s1, 0, 0, 0);
    }
    // ---- online softmax, state in regs (rows = quad lanes q*4+r) ----
    fx4 mx, alpha, p0, p1, sm;
#pragma unroll
    for (int r = 0; r < 4; ++r) mx[r] = fmaxf(s0[r], s1[r]);
#pragma unroll
    for (int d = 1; d < 16; d <<= 1) {
      mx[0] = fmaxf(mx[0], __shfl_xor(mx[0], d));
      mx[1] = fmaxf(mx[1], __shfl_xor(mx[1], d));
      mx[2] = fmaxf(mx[2], __shfl_xor(mx[2], d));
      mx[3] = fmaxf(mx[3], __shfl_xor(mx[3], d));
    }
    bool need = false;
#pragma unroll
    for (int r = 0; r < 4; ++r) {
      float mn = fmaxf(mrun[r], mx[r]);
      alpha[r] = __expf(mrun[r] - mn);
      mrun[r] = mn;
      p0[r] = __expf(s0[r] - mn);
      p1[r] = __expf(s1[r] - mn);
      sm[r] = p0[r] + p1[r];
      need |= (alpha[r] != 1.0f);
    }
#pragma unroll
    for (int d = 1; d < 16; d <<= 1) {
      sm[0] += __shfl_xor(sm[0], d);
      sm[1] += __shfl_xor(sm[1], d);
      sm[2] += __shfl_xor(sm[2], d);
      sm[3] += __shfl_xor(sm[3], d);
    }
#pragma unroll
    for (int r = 0; r < 4; ++r) lrun[r] = alpha[r] * lrun[r] + sm[r];
    // ---- P -> wave-private slab (no barrier: same-wave lgkm ordering) ----
#pragma unroll
    for (int r = 0; r < 4; ++r) {
      wp[(q * 4 + r) * 40 + ml] = f2h_bits(p0[r]);
      wp[(q * 4 + r) * 40 + 16 + ml] = f2h_bits(p1[r]);
    }
    // ---- rescale acc (skip when no row saw a new max) ----
    if (__any(need)) {
#pragma unroll
      for (int nj = 0; nj < 32; ++nj) {
        acc[nj][0] *= alpha[0]; acc[nj][1] *= alpha[1];
        acc[nj][2] *= alpha[2]; acc[nj][3] *= alpha[3];
      }
    }
    f16x8 pf = *(const f16x8*)(wp + ml * 40 + q * 8);
    // ---- PV over all 512 d (one shared pf) ----
#pragma unroll
    for (int nj = 0; nj < 32; ++nj) {
      f16x8 vf = *(const f16x8*)(sVc + (q * 512 + nj * 16 + ml) * 8);
      acc[nj] = __builtin_amdgcn_mfma_f32_16x16x32_f16(pf, vf, acc[nj], 0, 0, 0);
    }
    __syncthreads();  // single barrier: drains next-iter staging + buffer flip
  }
  // ---- epilogue: O = acc / l (all wave-private) ----
  fx4 linv;
#pragma unroll
  for (int r = 0; r < 4; ++r) linv[r] = 1.0f / lrun[r];
  float* Ob = O + (size_t)(w * 16 + q * 4) * 512 + ml;
#pragma unroll
  for (int nj = 0; nj < 32; ++nj) {
#pragma unroll
    for (int r = 0; r < 4; ++r)
      Ob[(size_t)r * 512 + nj * 16] = acc[nj][r] * linv[r];
  }
}

extern "C" void kernel_launch(void* const* d_in, const int* in_sizes, int n_in,
                              void* d_out, int out_size, void* d_ws, size_t ws_size,
                              hipStream_t stream) {
  // ws layout (u16 elems): [xh: 2*SZE][wt: 6*512*512][qkv: 6*SZE]
  //   qkv order: 0=Qr 1=Kr 2=Vr^T 3=Qh 4=Kh 5=Vh^T
  u16* ws = (u16*)d_ws;
  u16* xh = ws;
  u16* wt = ws + 16777216u;            // 2*SZE
  u16* qkv = ws + 18350080u;           // 2*SZE + 6*262144

  convert_x<<<8192, 256, 0, stream>>>((const float*)d_in[0],
                                      (const float*)d_in[1], xh);
  wtrans<<<dim3(16, 16, 6), dim3(32, 8), 0, stream>>>(
      (const float*)d_in[2], (const float*)d_in[4], (const float*)d_in[6],
      (const float*)d_in[8], (const float*)d_in[10], (const float*)d_in[12], wt);
  proj_gemm<<<dim3(128, 4, 6), 256, 0, stream>>>(
      xh, wt, qkv,
      (const float*)d_in[3], (const float*)d_in[5], (const float*)d_in[7],
      (const float*)d_in[9], (const float*)d_in[11], (const float*)d_in[13]);
  attn_kernel<<<256, 512, 0, stream>>>(qkv, (float*)d_out);
}